// Round 9
// baseline (1070.703 us; speedup 1.0000x reference)
//
#include <hip/hip_runtime.h>

// ---------------- problem constants ----------------
#define M_DIM 8192   // B*S = 4*2048
#define N_DIM 16384  // OUT
#define K_DIM 4096   // IN
#define QBLK  64     // bnb quant block

// GEMM geometry: 256x256 tile, BK=64, double-buffered LDS (8 regions x 16 KiB)
#define BM 256
#define BN 256
#define BK 64
#define NT (K_DIM / BK)   // 64 K-tiles

typedef short  s8v  __attribute__((ext_vector_type(8)));   // 8 bf16 (MFMA A/B frag)
typedef unsigned short u16x8 __attribute__((ext_vector_type(8)));
typedef float  f4v  __attribute__((ext_vector_type(4)));   // MFMA C/D frag

__constant__ float NF4C[16] = {
    -1.0f, -0.6961928009986877f, -0.5250730514526367f, -0.39491748809814453f,
    -0.28444138169288635f, -0.18477343022823334f, -0.09105003625154495f, 0.0f,
    0.07958029955625534f, 0.16093020141124725f, 0.24611230194568634f, 0.33791524171829224f,
    0.44070982933044434f, 0.5626170039176941f, 0.7229568362236023f, 1.0f
};

// round-to-nearest-even f32 -> bf16 bits (finite inputs only)
__device__ __forceinline__ unsigned short f2bf(float f) {
    union { float f; unsigned u; } v; v.f = f;
    unsigned r = v.u + 0x7FFFu + ((v.u >> 16) & 1u);
    return (unsigned short)(r >> 16);
}

__device__ __forceinline__ void async16(const unsigned short* g, unsigned short* l) {
    __builtin_amdgcn_global_load_lds(
        (const __attribute__((address_space(1))) void*)g,
        (__attribute__((address_space(3))) void*)l,
        16, 0, 0);
}

#define WAITVM(n)  asm volatile("s_waitcnt vmcnt(" #n ")" ::: "memory")
#define LGKM(n)    asm volatile("s_waitcnt lgkmcnt(" #n ")" ::: "memory")
#define BARX()     asm volatile("s_barrier" ::: "memory")
#define PRIO1      __builtin_amdgcn_s_setprio(1)
#define PRIO0      __builtin_amdgcn_s_setprio(0)

// ---------------- prep pass 1: x fp32 -> bf16 ----------------
__global__ void convert_x_kernel(const float* __restrict__ x,
                                 unsigned short* __restrict__ o, long n) {
    long i = ((long)blockIdx.x * blockDim.x + threadIdx.x) * 8;
    long stride = (long)gridDim.x * blockDim.x * 8;
    for (; i < n; i += stride) {
        const float4* p = (const float4*)(x + i);
        float4 a = p[0], b = p[1];
        u16x8 o8;
        o8[0] = f2bf(a.x); o8[1] = f2bf(a.y); o8[2] = f2bf(a.z); o8[3] = f2bf(a.w);
        o8[4] = f2bf(b.x); o8[5] = f2bf(b.y); o8[6] = f2bf(b.z); o8[7] = f2bf(b.w);
        *(u16x8*)(o + i) = o8;
    }
}

// ---------------- prep pass 2: NF4 codes -> bf16 weights ----------------
__global__ void dequant_w_kernel(const int* __restrict__ codes,
                                 const float* __restrict__ am,
                                 unsigned short* __restrict__ o, long n) {
    __shared__ float lut[16];
    if (threadIdx.x < 16) lut[threadIdx.x] = NF4C[threadIdx.x];
    __syncthreads();
    long i = ((long)blockIdx.x * blockDim.x + threadIdx.x) * 8;
    long stride = (long)gridDim.x * blockDim.x * 8;
    for (; i < n; i += stride) {
        const int4* p = (const int4*)(codes + i);
        int4 c0 = p[0], c1 = p[1];
        float s = am[i >> 6];
        u16x8 o8;
        o8[0] = f2bf(lut[c0.x] * s); o8[1] = f2bf(lut[c0.y] * s);
        o8[2] = f2bf(lut[c0.z] * s); o8[3] = f2bf(lut[c0.w] * s);
        o8[4] = f2bf(lut[c1.x] * s); o8[5] = f2bf(lut[c1.y] * s);
        o8[6] = f2bf(lut[c1.z] * s); o8[7] = f2bf(lut[c1.w] * s);
        *(u16x8*)(o + i) = o8;
    }
}

// ---------------- 8-phase 256x256 GEMM, 3-bit-swizzled LDS, L2-aware map ----
// y[m][n] = sum_k A[m][k]*B[n][k]; A [M][K], B [N][K] bf16 row-major.
// Identical to round-8 kernel EXCEPT the block->tile map: each XCD gets a
// 32M x 8N column stripe, m-fastest, so the ~32 concurrently-resident blocks
// of an XCD share ONE 2 MB B-tile (L2-resident) while streaming A. Cuts
// per-XCD L2-fill from ~136 MB (4Mx64N slab) to ~80 MB and total L2-side
// traffic ~2x.
//   xcd = bid&7 (dispatch round-robins XCDs), cidx = bid>>3 (sequential on
//   that XCD); bm0 = (cidx&31)*256, bn0 = (xcd*8 + cidx>>5)*256. Bijective.
// LDS: 8 regions x 16 KiB (buf0: A0=0 A1=1 B0=2 B1=3; buf1: +4). Region =
// row-major [128][64] bf16, swizzle stored_byte(row,k) = row*128 +
// ((k*2) ^ ((row&7)<<4)) -> conflict-free ds_read_b128 (round-8 verified: 0).
// Staging: linear dest; source row = i*64 + t/8 (coalesced 128B lines),
// source col = ((t&7)*8) ^ (((t>>3)&7)<<3). Fragment read:
// qL0 = fr*128 + (kg*16 ^ ((fr&7)<<4)); qL1 = qL0^64.
// Schedule: 8 phases / 2 K-tiles; stages A1^{t+1}, A0/B0/B1^{t+2}, A1^{t+2},
// A0/B0/B1^{t+3}; vmcnt(6) at ph4/ph8; lgkmcnt(8) after 12-read phases; last
// iteration k-offsets clamped.
__global__ __launch_bounds__(512, 2)
void gemm_8swz_kernel(const unsigned short* __restrict__ A,
                      const unsigned short* __restrict__ B,
                      float* __restrict__ Cp) {
    __shared__ __attribute__((aligned(16))) unsigned short lds[65536]; // 128 KiB

    const int tid  = threadIdx.x;
    const int wid  = tid >> 6;
    const int lane = tid & 63;
    const int wm   = wid >> 2;   // 0..1
    const int wn   = wid & 3;    // 0..3

    // L2-aware XCD map: column stripe per XCD, m-fastest
    const int bid  = blockIdx.x;
    const int xcd  = bid & 7;
    const int cidx = bid >> 3;                 // 0..255 sequential per XCD
    const int bm0  = (cidx & 31) * BM;         // 32 m-tiles, fastest
    const int bn0  = (xcd * 8 + (cidx >> 5)) * BN;  // 8 n-tiles per XCD

    // staging source coords (linear dest, inverse-swizzled source column)
    const int scol = ((tid & 7) * 8) ^ (((tid >> 3) & 7) << 3);
    int Rr[2];
    Rr[0] = tid >> 3;          // rows 0..63   (instr i=0)
    Rr[1] = 64 + (tid >> 3);   // rows 64..127 (instr i=1); (row&7) unchanged

    const unsigned short* pA0[2]; const unsigned short* pA1[2];
    const unsigned short* pB0[2]; const unsigned short* pB1[2];
#pragma unroll
    for (int i = 0; i < 2; ++i) {
        pA0[i] = A + (size_t)(bm0 + Rr[i]) * K_DIM + scol;
        pA1[i] = pA0[i] + (size_t)128 * K_DIM;
        pB0[i] = B + (size_t)(bn0 + Rr[i]) * K_DIM + scol;
        pB1[i] = pB0[i] + (size_t)128 * K_DIM;
    }

    // stage one half-tile (2 global_load_lds) into region R at k-offset KO;
    // dest base is wave-uniform (HW adds lane*16)
#define STG(R, P, KO)                                                         \
    { unsigned short* d = lds + (R) * 8192 + wid * 512;                       \
      async16(P[0] + (KO), d);                                                \
      async16(P[1] + (KO), d + 4096); }

    // fragment read byte offsets (swizzled); kk=1 (k+32) flips bit 6
    const int fr = lane & 15, kg = lane >> 4;
    const int qL0 = fr * 128 + ((kg * 16) ^ ((fr & 7) << 4));
    const int qL1 = qL0 ^ 64;
    const char* ldsc = (const char*)lds;

    f4v acc[8][4];
#pragma unroll
    for (int i = 0; i < 8; ++i)
#pragma unroll
        for (int j = 0; j < 4; ++j) acc[i][j] = f4v{0.f, 0.f, 0.f, 0.f};

    s8v aset[4][2], b0set[2][2], b1set[2][2];

    // A quadrant in region R: wave wm rows wm*64 + fm*16 + fr, k = kk*32+kg*8
#define RD_A(R)                                                               \
    { const char* ba = ldsc + (R) * 16384 + wm * 8192;                        \
      _Pragma("unroll") for (int fm = 0; fm < 4; ++fm) {                      \
          aset[fm][0] = *(const s8v*)(ba + fm * 2048 + qL0);                  \
          aset[fm][1] = *(const s8v*)(ba + fm * 2048 + qL1); } }

    // B quadrant in region R: wave wn rows wn*32 + fn*16 + fr
#define RD_B(R, BS)                                                           \
    { const char* bb = ldsc + (R) * 16384 + wn * 4096;                        \
      _Pragma("unroll") for (int fn = 0; fn < 2; ++fn) {                      \
          BS[fn][0] = *(const s8v*)(bb + fn * 2048 + qL0);                    \
          BS[fn][1] = *(const s8v*)(bb + fn * 2048 + qL1); } }

#define MM(qm, qn, BS)                                                        \
    _Pragma("unroll") for (int kk = 0; kk < 2; ++kk)                          \
      _Pragma("unroll") for (int fm = 0; fm < 4; ++fm)                        \
        _Pragma("unroll") for (int fn = 0; fn < 2; ++fn)                      \
          acc[(qm)*4+fm][(qn)*2+fn] = __builtin_amdgcn_mfma_f32_16x16x32_bf16(\
            aset[fm][kk], BS[fn][kk], acc[(qm)*4+fm][(qn)*2+fn], 0, 0, 0);

    // ---- prologue: tile0 (4 halves) + A0,B0,B1 of tile1; retire tile0 ----
    STG(0, pA0, 0); STG(2, pB0, 0); STG(3, pB1, 0); STG(1, pA1, 0);
    STG(4, pA0, BK); STG(6, pB0, BK); STG(7, pB1, BK);
    WAITVM(6);
    BARX();

    for (int i2 = 0; i2 < NT / 2; ++i2) {
        const int t  = 2 * i2;
        const int k1 = (t + 1) * BK;                              // <= (NT-1)*BK
        const int k2 = ((t + 2 < NT) ? (t + 2) : (NT - 1)) * BK;  // clamped
        const int k3 = ((t + 3 < NT) ? (t + 3) : (NT - 1)) * BK;  // clamped

        // ======== tile t (buf0: A0=0 A1=1 B0=2 B1=3) ========
        // ph1: Q00
        RD_A(0); RD_B(2, b0set);
        STG(5, pA1, k1);                 // A1^{t+1} -> buf1
        LGKM(8);
        BARX(); LGKM(0);
        PRIO1; MM(0, 0, b0set); PRIO0;
        BARX();
        // ph2: Q01
        RD_B(3, b1set);
        STG(0, pA0, k2);                 // A0^{t+2} -> buf0
        BARX(); LGKM(0);
        PRIO1; MM(0, 1, b1set); PRIO0;
        BARX();
        // ph3: Q11
        RD_A(1);
        STG(2, pB0, k2);                 // B0^{t+2}
        BARX(); LGKM(0);
        PRIO1; MM(1, 1, b1set); PRIO0;
        BARX();
        // ph4: Q10 (register-resident operands)
        STG(3, pB1, k2);                 // B1^{t+2}
        BARX();
        PRIO1; MM(1, 0, b0set); PRIO0;
        WAITVM(6);                       // retire tile t+1's 4 halves
        BARX();

        // ======== tile t+1 (buf1: A0=4 A1=5 B0=6 B1=7) ========
        // ph5: Q00
        RD_A(4); RD_B(6, b0set);
        STG(1, pA1, k2);                 // A1^{t+2} -> buf0
        LGKM(8);
        BARX(); LGKM(0);
        PRIO1; MM(0, 0, b0set); PRIO0;
        BARX();
        // ph6: Q01
        RD_B(7, b1set);
        STG(4, pA0, k3);                 // A0^{t+3} -> buf1
        BARX(); LGKM(0);
        PRIO1; MM(0, 1, b1set); PRIO0;
        BARX();
        // ph7: Q11
        RD_A(5);
        STG(6, pB0, k3);                 // B0^{t+3}
        BARX(); LGKM(0);
        PRIO1; MM(1, 1, b1set); PRIO0;
        BARX();
        // ph8: Q10
        STG(7, pB1, k3);                 // B1^{t+3}
        BARX();
        PRIO1; MM(1, 0, b0set); PRIO0;
        WAITVM(6);                       // retire tile t+2's 4 halves
        BARX();
    }

    // ---- epilogue: D col = lane&15, row = (lane>>4)*4 + r ----
#pragma unroll
    for (int m8 = 0; m8 < 8; ++m8) {
        const int grow = bm0 + (m8 >> 2) * 128 + wm * 64 + (m8 & 3) * 16 + (lane >> 4) * 4;
#pragma unroll
        for (int n4 = 0; n4 < 4; ++n4) {
            const int gcol = bn0 + (n4 >> 1) * 128 + wn * 32 + (n4 & 1) * 16 + (lane & 15);
            float* yp = Cp + (size_t)grow * N_DIM + gcol;
#pragma unroll
            for (int r = 0; r < 4; ++r) yp[(size_t)r * N_DIM] = acc[m8][n4][r];
        }
    }
#undef STG
#undef RD_A
#undef RD_B
#undef MM
}

// ---------------- fallback: fused dequant GEMM (no workspace needed) ----------------
__global__ void gemm_fused_kernel(const float* __restrict__ X,
                                  const int* __restrict__ W,
                                  const float* __restrict__ am,
                                  float* __restrict__ C) {
    __shared__ __attribute__((aligned(16))) unsigned short ldsA[128 * 32];
    __shared__ __attribute__((aligned(16))) unsigned short ldsB[128 * 32];
    __shared__ float lut[16];

    const int tid = threadIdx.x;
    if (tid < 16) lut[tid] = NF4C[tid];
    __syncthreads();

    const int wave = tid >> 6, lane = tid & 63;
    const int wr = wave >> 1, wc = wave & 1;
    const int bid = blockIdx.x;
    const int wg  = (bid & 7) * 1024 + (bid >> 3);
    const int bm0 = (wg >> 7) * 128;
    const int bn0 = (wg & 127) * 128;

    const int row = tid >> 2, col8 = (tid & 3) * 8;
    const float* gX0 = X + (size_t)(bm0 + row) * K_DIM + col8;
    const float* gX1 = gX0 + (size_t)64 * K_DIM;
    const int*   gW0 = W + (size_t)(bn0 + row) * K_DIM + col8;
    const int*   gW1 = gW0 + (size_t)64 * K_DIM;
    const int amRow0 = (bn0 + row) * (K_DIM / QBLK);
    const int amRow1 = (bn0 + row + 64) * (K_DIM / QBLK);

    unsigned short* sA0 = ldsA + tid * 8;
    unsigned short* sA1 = ldsA + (tid + 256) * 8;
    unsigned short* sB0 = ldsB + tid * 8;
    unsigned short* sB1 = ldsB + (tid + 256) * 8;

    f4v acc[4][4];
#pragma unroll
    for (int i = 0; i < 4; ++i)
#pragma unroll
        for (int j = 0; j < 4; ++j) acc[i][j] = f4v{0.f, 0.f, 0.f, 0.f};

    const int fr = lane & 15, kg = lane >> 4;
    const unsigned short* pa = ldsA + (wr * 64 + fr) * 32 + kg * 8;
    const unsigned short* pb = ldsB + (wc * 64 + fr) * 32 + kg * 8;

    for (int k0 = 0; k0 < K_DIM; k0 += 32) {
        float4 x0a = *(const float4*)(gX0 + k0);
        float4 x0b = *(const float4*)(gX0 + k0 + 4);
        float4 x1a = *(const float4*)(gX1 + k0);
        float4 x1b = *(const float4*)(gX1 + k0 + 4);
        int4 w0a = *(const int4*)(gW0 + k0);
        int4 w0b = *(const int4*)(gW0 + k0 + 4);
        int4 w1a = *(const int4*)(gW1 + k0);
        int4 w1b = *(const int4*)(gW1 + k0 + 4);
        float s0 = am[amRow0 + ((k0 + col8) >> 6)];
        float s1 = am[amRow1 + ((k0 + col8) >> 6)];

        u16x8 A0, A1, B0, B1;
        A0[0] = f2bf(x0a.x); A0[1] = f2bf(x0a.y); A0[2] = f2bf(x0a.z); A0[3] = f2bf(x0a.w);
        A0[4] = f2bf(x0b.x); A0[5] = f2bf(x0b.y); A0[6] = f2bf(x0b.z); A0[7] = f2bf(x0b.w);
        A1[0] = f2bf(x1a.x); A1[1] = f2bf(x1a.y); A1[2] = f2bf(x1a.z); A1[3] = f2bf(x1a.w);
        A1[4] = f2bf(x1b.x); A1[5] = f2bf(x1b.y); A1[6] = f2bf(x1b.z); A1[7] = f2bf(x1b.w);
        B0[0] = f2bf(lut[w0a.x] * s0); B0[1] = f2bf(lut[w0a.y] * s0);
        B0[2] = f2bf(lut[w0a.z] * s0); B0[3] = f2bf(lut[w0a.w] * s0);
        B0[4] = f2bf(lut[w0b.x] * s0); B0[5] = f2bf(lut[w0b.y] * s0);
        B0[6] = f2bf(lut[w0b.z] * s0); B0[7] = f2bf(lut[w0b.w] * s0);
        B1[0] = f2bf(lut[w1a.x] * s1); B1[1] = f2bf(lut[w1a.y] * s1);
        B1[2] = f2bf(lut[w1a.z] * s1); B1[3] = f2bf(lut[w1a.w] * s1);
        B1[4] = f2bf(lut[w1b.x] * s1); B1[5] = f2bf(lut[w1b.y] * s1);
        B1[6] = f2bf(lut[w1b.z] * s1); B1[7] = f2bf(lut[w1b.w] * s1);

        __syncthreads();
        *(u16x8*)sA0 = A0; *(u16x8*)sA1 = A1;
        *(u16x8*)sB0 = B0; *(u16x8*)sB1 = B1;
        __syncthreads();

        s8v a[4], b[4];
#pragma unroll
        for (int i = 0; i < 4; ++i) a[i] = *(const s8v*)(pa + i * 16 * 32);
#pragma unroll
        for (int i = 0; i < 4; ++i) b[i] = *(const s8v*)(pb + i * 16 * 32);
#pragma unroll
        for (int i = 0; i < 4; ++i)
#pragma unroll
            for (int j = 0; j < 4; ++j)
                acc[i][j] = __builtin_amdgcn_mfma_f32_16x16x32_bf16(a[i], b[j], acc[i][j], 0, 0, 0);
    }

    const int row0 = bm0 + wr * 64 + (lane >> 4) * 4;
    const int col0 = bn0 + wc * 64 + (lane & 15);
#pragma unroll
    for (int i = 0; i < 4; ++i)
#pragma unroll
        for (int j = 0; j < 4; ++j) {
            float* yp = C + (size_t)(row0 + i * 16) * N_DIM + col0 + j * 16;
#pragma unroll
            for (int r = 0; r < 4; ++r) yp[(size_t)r * N_DIM] = acc[i][j][r];
        }
}

extern "C" void kernel_launch(void* const* d_in, const int* in_sizes, int n_in,
                              void* d_out, int out_size, void* d_ws, size_t ws_size,
                              hipStream_t stream) {
    const float* x     = (const float*)d_in[0];
    const int*   codes = (const int*)d_in[1];
    const float* am    = (const float*)d_in[2];
    float* y = (float*)d_out;

    const long MK = (long)M_DIM * K_DIM;
    const long NK = (long)N_DIM * K_DIM;
    const size_t need = (size_t)(MK + NK) * sizeof(unsigned short);  // 192 MiB

    if (ws_size >= need) {
        unsigned short* xb = (unsigned short*)d_ws;
        unsigned short* wb = xb + MK;
        convert_x_kernel<<<2048, 256, 0, stream>>>(x, xb, MK);
        dequant_w_kernel<<<2048, 256, 0, stream>>>(codes, am, wb, NK);
        const int ngrid = (M_DIM / BM) * (N_DIM / BN);  // 2048
        gemm_8swz_kernel<<<ngrid, 512, 0, stream>>>(xb, wb, y);
    } else {
        const int ngrid = (M_DIM / 128) * (N_DIM / 128); // 8192
        gemm_fused_kernel<<<ngrid, 256, 0, stream>>>(x, codes, am, y);
    }
}

// Round 10
// 1015.890 us; speedup vs baseline: 1.0540x; 1.0540x over previous
//
#include <hip/hip_runtime.h>

// ---------------- problem constants ----------------
#define M_DIM 8192   // B*S = 4*2048
#define N_DIM 16384  // OUT
#define K_DIM 4096   // IN
#define QBLK  64     // bnb quant block

// GEMM geometry: 256x256 tile, BK=64, double-buffered LDS (8 regions x 16 KiB)
#define BM 256
#define BN 256
#define BK 64
#define NT (K_DIM / BK)   // 64 K-tiles

typedef short  s8v  __attribute__((ext_vector_type(8)));   // 8 bf16 (MFMA A/B frag)
typedef unsigned short u16x8 __attribute__((ext_vector_type(8)));
typedef float  f4v  __attribute__((ext_vector_type(4)));   // MFMA C/D frag

__constant__ float NF4C[16] = {
    -1.0f, -0.6961928009986877f, -0.5250730514526367f, -0.39491748809814453f,
    -0.28444138169288635f, -0.18477343022823334f, -0.09105003625154495f, 0.0f,
    0.07958029955625534f, 0.16093020141124725f, 0.24611230194568634f, 0.33791524171829224f,
    0.44070982933044434f, 0.5626170039176941f, 0.7229568362236023f, 1.0f
};

// round-to-nearest-even f32 -> bf16 bits (finite inputs only)
__device__ __forceinline__ unsigned short f2bf(float f) {
    union { float f; unsigned u; } v; v.f = f;
    unsigned r = v.u + 0x7FFFu + ((v.u >> 16) & 1u);
    return (unsigned short)(r >> 16);
}

__device__ __forceinline__ void async16(const unsigned short* g, unsigned short* l) {
    __builtin_amdgcn_global_load_lds(
        (const __attribute__((address_space(1))) void*)g,
        (__attribute__((address_space(3))) void*)l,
        16, 0, 0);
}

#define WAITVM(n)  asm volatile("s_waitcnt vmcnt(" #n ")" ::: "memory")
#define BARX()     asm volatile("s_barrier" ::: "memory")
#define PRIO1      __builtin_amdgcn_s_setprio(1)
#define PRIO0      __builtin_amdgcn_s_setprio(0)

// ---------------- prep pass 1: x fp32 -> bf16 ----------------
__global__ void convert_x_kernel(const float* __restrict__ x,
                                 unsigned short* __restrict__ o, long n) {
    long i = ((long)blockIdx.x * blockDim.x + threadIdx.x) * 8;
    long stride = (long)gridDim.x * blockDim.x * 8;
    for (; i < n; i += stride) {
        const float4* p = (const float4*)(x + i);
        float4 a = p[0], b = p[1];
        u16x8 o8;
        o8[0] = f2bf(a.x); o8[1] = f2bf(a.y); o8[2] = f2bf(a.z); o8[3] = f2bf(a.w);
        o8[4] = f2bf(b.x); o8[5] = f2bf(b.y); o8[6] = f2bf(b.z); o8[7] = f2bf(b.w);
        *(u16x8*)(o + i) = o8;
    }
}

// ---------------- prep pass 2: NF4 codes -> bf16 weights ----------------
__global__ void dequant_w_kernel(const int* __restrict__ codes,
                                 const float* __restrict__ am,
                                 unsigned short* __restrict__ o, long n) {
    __shared__ float lut[16];
    if (threadIdx.x < 16) lut[threadIdx.x] = NF4C[threadIdx.x];
    __syncthreads();
    long i = ((long)blockIdx.x * blockDim.x + threadIdx.x) * 8;
    long stride = (long)gridDim.x * blockDim.x * 8;
    for (; i < n; i += stride) {
        const int4* p = (const int4*)(codes + i);
        int4 c0 = p[0], c1 = p[1];
        float s = am[i >> 6];
        u16x8 o8;
        o8[0] = f2bf(lut[c0.x] * s); o8[1] = f2bf(lut[c0.y] * s);
        o8[2] = f2bf(lut[c0.z] * s); o8[3] = f2bf(lut[c0.w] * s);
        o8[4] = f2bf(lut[c1.x] * s); o8[5] = f2bf(lut[c1.y] * s);
        o8[6] = f2bf(lut[c1.z] * s); o8[7] = f2bf(lut[c1.w] * s);
        *(u16x8*)(o + i) = o8;
    }
}

// ---------------- 3-phase 256x256 GEMM, swizzled linear LDS ----------------
// y[m][n] = sum_k A[m][k]*B[n][k]; A [M][K], B [N][K] bf16 row-major.
// Round-8 LDS layout + round-8 block map + round-4 LOW-SYNC schedule:
// 3 barriers per K-tile (vs 8), NO explicit lgkmcnt drains (compiler emits
// fine-grained per-MFMA waits, so MFMA #1 starts while later reads fly).
// LDS: 8 regions x 16 KiB (buf0: A0=0 A1=1 B0=2 B1=3; buf1: +4). Region =
// row-major [128][64] bf16, swizzle stored_byte(row,k) = row*128 +
// ((k*2) ^ ((row&7)<<4)) -> conflict-free ds_read_b128 (round-8: 0 conflicts).
// Staging: linear global_load_lds dest; source row = i*64 + tid/8 (coalesced
// full 128B lines), source col = ((tid&7)*8) ^ (((tid>>3)&7)<<3).
// Fragment read: qL0 = fr*128 + (kg*16 ^ ((fr&7)<<4)); qL1 = qL0 ^ 64.
// Schedule per K-tile t (stages tile t+1 into buf (t+1)&1):
//   ph0 : RD A0,B0 | STG A0' | MM Q00 | vm4 | bar
//   ph1 : RD B1    | STG B0' | MM Q01 | vm4 | bar
//   ph23: RD A1    | STG B1' | MM Q11 | STG A1' | MM Q10 | vm4 | bar
// Ledger (2 loads/STG, verified): each vm4 retires exactly the halves the
// next phase reads (A0'+B0' at ph23-end after 8 in flight; B1' at ph0-end;
// A1' at ph1-end); RAW lead = 3 phases; WAR >= 3 barriers. Tail: vm2, vm0.
__global__ __launch_bounds__(512, 2)
void gemm_3pswz_kernel(const unsigned short* __restrict__ A,
                       const unsigned short* __restrict__ B,
                       float* __restrict__ Cp) {
    __shared__ __attribute__((aligned(16))) unsigned short lds[65536]; // 128 KiB

    const int tid  = threadIdx.x;
    const int wid  = tid >> 6;
    const int lane = tid & 63;
    const int wm   = wid >> 2;   // 0..1
    const int wn   = wid & 3;    // 0..3

    // XCD-bijective swizzle (round-8, best measured): chunk 256 per XCD
    const int bid = blockIdx.x;
    const int wg  = (bid & 7) * 256 + (bid >> 3);
    const int bm0 = (wg >> 6) * BM;
    const int bn0 = (wg & 63) * BN;

    // staging source coords (linear dest, inverse-swizzled source column)
    const int scol = ((tid & 7) * 8) ^ (((tid >> 3) & 7) << 3);
    int Rr[2];
    Rr[0] = tid >> 3;          // rows 0..63   (instr i=0)
    Rr[1] = 64 + (tid >> 3);   // rows 64..127 (instr i=1); (row&7) unchanged

    const unsigned short* pA0[2]; const unsigned short* pA1[2];
    const unsigned short* pB0[2]; const unsigned short* pB1[2];
#pragma unroll
    for (int i = 0; i < 2; ++i) {
        pA0[i] = A + (size_t)(bm0 + Rr[i]) * K_DIM + scol;
        pA1[i] = pA0[i] + (size_t)128 * K_DIM;
        pB0[i] = B + (size_t)(bn0 + Rr[i]) * K_DIM + scol;
        pB1[i] = pB0[i] + (size_t)128 * K_DIM;
    }

    // stage one half-tile (2 global_load_lds) into region R at k-offset KO;
    // dest base is wave-uniform (HW adds lane*16)
#define STG(R, P, KO)                                                         \
    { unsigned short* d = lds + (R) * 8192 + wid * 512;                       \
      async16(P[0] + (KO), d);                                                \
      async16(P[1] + (KO), d + 4096); }

    // fragment read byte offsets (swizzled); kk=1 (k+32) flips bit 6
    const int fr = lane & 15, kg = lane >> 4;
    const int qL0 = fr * 128 + ((kg * 16) ^ ((fr & 7) << 4));
    const int qL1 = qL0 ^ 64;
    const char* ldsc = (const char*)lds;

    f4v acc[8][4];
#pragma unroll
    for (int i = 0; i < 8; ++i)
#pragma unroll
        for (int j = 0; j < 4; ++j) acc[i][j] = f4v{0.f, 0.f, 0.f, 0.f};

    s8v aset[4][2], b0set[2][2], b1set[2][2];

    // A quadrant in region R: wave wm rows wm*64 + fm*16 + fr, k = kk*32+kg*8
#define RD_A(R)                                                               \
    { const char* ba = ldsc + (R) * 16384 + wm * 8192;                        \
      _Pragma("unroll") for (int fm = 0; fm < 4; ++fm) {                      \
          aset[fm][0] = *(const s8v*)(ba + fm * 2048 + qL0);                  \
          aset[fm][1] = *(const s8v*)(ba + fm * 2048 + qL1); } }

    // B quadrant in region R: wave wn rows wn*32 + fn*16 + fr
#define RD_B(R, BS)                                                           \
    { const char* bb = ldsc + (R) * 16384 + wn * 4096;                        \
      _Pragma("unroll") for (int fn = 0; fn < 2; ++fn) {                      \
          BS[fn][0] = *(const s8v*)(bb + fn * 2048 + qL0);                    \
          BS[fn][1] = *(const s8v*)(bb + fn * 2048 + qL1); } }

#define MM(qm, qn, BS)                                                        \
    _Pragma("unroll") for (int kk = 0; kk < 2; ++kk)                          \
      _Pragma("unroll") for (int fm = 0; fm < 4; ++fm)                        \
        _Pragma("unroll") for (int fn = 0; fn < 2; ++fn)                      \
          acc[(qm)*4+fm][(qn)*2+fn] = __builtin_amdgcn_mfma_f32_16x16x32_bf16(\
            aset[fm][kk], BS[fn][kk], acc[(qm)*4+fm][(qn)*2+fn], 0, 0, 0);

    // ---- prologue: stage tile 0 into buf0; drain; barrier ----
    STG(0, pA0, 0); STG(2, pB0, 0); STG(3, pB1, 0); STG(1, pA1, 0);
    WAITVM(0);
    BARX();

    for (int t = 0; t < NT - 1; ++t) {
        const int b4 = (t & 1) * 4;
        const int n4 = 4 - b4;
        const int kn = (t + 1) * BK;

        // ---- ph0: Q00 ----
        RD_A(b4 + 0); RD_B(b4 + 2, b0set);
        STG(n4 + 0, pA0, kn);            // A0^{t+1}
        PRIO1; MM(0, 0, b0set); PRIO0;
        WAITVM(4); BARX();

        // ---- ph1: Q01 ----
        RD_B(b4 + 3, b1set);
        STG(n4 + 2, pB0, kn);            // B0^{t+1}
        PRIO1; MM(0, 1, b1set); PRIO0;
        WAITVM(4); BARX();

        // ---- ph23: Q11 then Q10 ----
        RD_A(b4 + 1);
        STG(n4 + 3, pB1, kn);            // B1^{t+1}
        PRIO1; MM(1, 1, b1set); PRIO0;
        STG(n4 + 1, pA1, kn);            // A1^{t+1}
        PRIO1; MM(1, 0, b0set); PRIO0;
        WAITVM(4); BARX();
    }

    // ---- tail tile NT-1 (no staging; shrinking waits) ----
    {
        const int b4 = ((NT - 1) & 1) * 4;
        RD_A(b4 + 0); RD_B(b4 + 2, b0set);
        PRIO1; MM(0, 0, b0set); PRIO0;
        WAITVM(2); BARX();
        RD_B(b4 + 3, b1set);
        PRIO1; MM(0, 1, b1set); PRIO0;
        WAITVM(0); BARX();
        RD_A(b4 + 1);
        PRIO1; MM(1, 1, b1set); MM(1, 0, b0set); PRIO0;
    }

    // ---- epilogue: D col = lane&15, row = (lane>>4)*4 + r ----
#pragma unroll
    for (int m8 = 0; m8 < 8; ++m8) {
        const int grow = bm0 + (m8 >> 2) * 128 + wm * 64 + (m8 & 3) * 16 + (lane >> 4) * 4;
#pragma unroll
        for (int n4 = 0; n4 < 4; ++n4) {
            const int gcol = bn0 + (n4 >> 1) * 128 + wn * 32 + (n4 & 1) * 16 + (lane & 15);
            float* yp = Cp + (size_t)grow * N_DIM + gcol;
#pragma unroll
            for (int r = 0; r < 4; ++r) yp[(size_t)r * N_DIM] = acc[m8][n4][r];
        }
    }
#undef STG
#undef RD_A
#undef RD_B
#undef MM
}

// ---------------- fallback: fused dequant GEMM (no workspace needed) ----------------
__global__ void gemm_fused_kernel(const float* __restrict__ X,
                                  const int* __restrict__ W,
                                  const float* __restrict__ am,
                                  float* __restrict__ C) {
    __shared__ __attribute__((aligned(16))) unsigned short ldsA[128 * 32];
    __shared__ __attribute__((aligned(16))) unsigned short ldsB[128 * 32];
    __shared__ float lut[16];

    const int tid = threadIdx.x;
    if (tid < 16) lut[tid] = NF4C[tid];
    __syncthreads();

    const int wave = tid >> 6, lane = tid & 63;
    const int wr = wave >> 1, wc = wave & 1;
    const int bid = blockIdx.x;
    const int wg  = (bid & 7) * 1024 + (bid >> 3);
    const int bm0 = (wg >> 7) * 128;
    const int bn0 = (wg & 127) * 128;

    const int row = tid >> 2, col8 = (tid & 3) * 8;
    const float* gX0 = X + (size_t)(bm0 + row) * K_DIM + col8;
    const float* gX1 = gX0 + (size_t)64 * K_DIM;
    const int*   gW0 = W + (size_t)(bn0 + row) * K_DIM + col8;
    const int*   gW1 = gW0 + (size_t)64 * K_DIM;
    const int amRow0 = (bn0 + row) * (K_DIM / QBLK);
    const int amRow1 = (bn0 + row + 64) * (K_DIM / QBLK);

    unsigned short* sA0 = ldsA + tid * 8;
    unsigned short* sA1 = ldsA + (tid + 256) * 8;
    unsigned short* sB0 = ldsB + tid * 8;
    unsigned short* sB1 = ldsB + (tid + 256) * 8;

    f4v acc[4][4];
#pragma unroll
    for (int i = 0; i < 4; ++i)
#pragma unroll
        for (int j = 0; j < 4; ++j) acc[i][j] = f4v{0.f, 0.f, 0.f, 0.f};

    const int fr = lane & 15, kg = lane >> 4;
    const unsigned short* pa = ldsA + (wr * 64 + fr) * 32 + kg * 8;
    const unsigned short* pb = ldsB + (wc * 64 + fr) * 32 + kg * 8;

    for (int k0 = 0; k0 < K_DIM; k0 += 32) {
        float4 x0a = *(const float4*)(gX0 + k0);
        float4 x0b = *(const float4*)(gX0 + k0 + 4);
        float4 x1a = *(const float4*)(gX1 + k0);
        float4 x1b = *(const float4*)(gX1 + k0 + 4);
        int4 w0a = *(const int4*)(gW0 + k0);
        int4 w0b = *(const int4*)(gW0 + k0 + 4);
        int4 w1a = *(const int4*)(gW1 + k0);
        int4 w1b = *(const int4*)(gW1 + k0 + 4);
        float s0 = am[amRow0 + ((k0 + col8) >> 6)];
        float s1 = am[amRow1 + ((k0 + col8) >> 6)];

        u16x8 A0, A1, B0, B1;
        A0[0] = f2bf(x0a.x); A0[1] = f2bf(x0a.y); A0[2] = f2bf(x0a.z); A0[3] = f2bf(x0a.w);
        A0[4] = f2bf(x0b.x); A0[5] = f2bf(x0b.y); A0[6] = f2bf(x0b.z); A0[7] = f2bf(x0b.w);
        A1[0] = f2bf(x1a.x); A1[1] = f2bf(x1a.y); A1[2] = f2bf(x1a.z); A1[3] = f2bf(x1a.w);
        A1[4] = f2bf(x1b.x); A1[5] = f2bf(x1b.y); A1[6] = f2bf(x1b.z); A1[7] = f2bf(x1b.w);
        B0[0] = f2bf(lut[w0a.x] * s0); B0[1] = f2bf(lut[w0a.y] * s0);
        B0[2] = f2bf(lut[w0a.z] * s0); B0[3] = f2bf(lut[w0a.w] * s0);
        B0[4] = f2bf(lut[w0b.x] * s0); B0[5] = f2bf(lut[w0b.y] * s0);
        B0[6] = f2bf(lut[w0b.z] * s0); B0[7] = f2bf(lut[w0b.w] * s0);
        B1[0] = f2bf(lut[w1a.x] * s1); B1[1] = f2bf(lut[w1a.y] * s1);
        B1[2] = f2bf(lut[w1a.z] * s1); B1[3] = f2bf(lut[w1a.w] * s1);
        B1[4] = f2bf(lut[w1b.x] * s1); B1[5] = f2bf(lut[w1b.y] * s1);
        B1[6] = f2bf(lut[w1b.z] * s1); B1[7] = f2bf(lut[w1b.w] * s1);

        __syncthreads();
        *(u16x8*)sA0 = A0; *(u16x8*)sA1 = A1;
        *(u16x8*)sB0 = B0; *(u16x8*)sB1 = B1;
        __syncthreads();

        s8v a[4], b[4];
#pragma unroll
        for (int i = 0; i < 4; ++i) a[i] = *(const s8v*)(pa + i * 16 * 32);
#pragma unroll
        for (int i = 0; i < 4; ++i) b[i] = *(const s8v*)(pb + i * 16 * 32);
#pragma unroll
        for (int i = 0; i < 4; ++i)
#pragma unroll
            for (int j = 0; j < 4; ++j)
                acc[i][j] = __builtin_amdgcn_mfma_f32_16x16x32_bf16(a[i], b[j], acc[i][j], 0, 0, 0);
    }

    const int row0 = bm0 + wr * 64 + (lane >> 4) * 4;
    const int col0 = bn0 + wc * 64 + (lane & 15);
#pragma unroll
    for (int i = 0; i < 4; ++i)
#pragma unroll
        for (int j = 0; j < 4; ++j) {
            float* yp = C + (size_t)(row0 + i * 16) * N_DIM + col0 + j * 16;
#pragma unroll
            for (int r = 0; r < 4; ++r) yp[(size_t)r * N_DIM] = acc[i][j][r];
        }
}

extern "C" void kernel_launch(void* const* d_in, const int* in_sizes, int n_in,
                              void* d_out, int out_size, void* d_ws, size_t ws_size,
                              hipStream_t stream) {
    const float* x     = (const float*)d_in[0];
    const int*   codes = (const int*)d_in[1];
    const float* am    = (const float*)d_in[2];
    float* y = (float*)d_out;

    const long MK = (long)M_DIM * K_DIM;
    const long NK = (long)N_DIM * K_DIM;
    const size_t need = (size_t)(MK + NK) * sizeof(unsigned short);  // 192 MiB

    if (ws_size >= need) {
        unsigned short* xb = (unsigned short*)d_ws;
        unsigned short* wb = xb + MK;
        convert_x_kernel<<<2048, 256, 0, stream>>>(x, xb, MK);
        dequant_w_kernel<<<2048, 256, 0, stream>>>(codes, am, wb, NK);
        const int ngrid = (M_DIM / BM) * (N_DIM / BN);  // 2048
        gemm_3pswz_kernel<<<ngrid, 512, 0, stream>>>(xb, wb, y);
    } else {
        const int ngrid = (M_DIM / 128) * (N_DIM / 128); // 8192
        gemm_fused_kernel<<<ngrid, 256, 0, stream>>>(x, codes, am, y);
    }
}